// Round 2
// baseline (9621.141 us; speedup 1.0000x reference)
//
#include <hip/hip_runtime.h>
#include <hip/hip_bf16.h>
#include <math.h>

// GPT-2 small fwd: V=50257 D=768 H=12 F=3072 L=6 S=1024 B=2
constexpr int V  = 50257;
constexpr int D  = 768;
constexpr int H  = 12;
constexpr int F  = 3072;
constexpr int L  = 6;
constexpr int S  = 1024;
constexpr int B  = 2;
constexpr int DH = 64;
constexpr int M  = B * S;   // 2048 rows
constexpr float EPS = 1e-5f;

// ---------------------------------------------------------------- embedding
__global__ void embed_k(const int* __restrict__ ids, const float* __restrict__ wte,
                        const float* __restrict__ wpe, float* __restrict__ x) {
    int row = blockIdx.x;              // 0..M-1
    int s   = row & (S - 1);
    int id  = ids[row];
    const float* we = wte + (size_t)id * D;
    const float* wp = wpe + (size_t)s * D;
    float* xo = x + (size_t)row * D;
    for (int i = threadIdx.x; i < D; i += 256) xo[i] = we[i] + wp[i];
}

// ---------------------------------------------------------------- layernorm
__global__ __launch_bounds__(256) void ln_k(const float* __restrict__ in, float* __restrict__ out,
                                            const float* __restrict__ g, const float* __restrict__ bb) {
    __shared__ float r1[256], r2[256];
    int row = blockIdx.x;
    int tid = threadIdx.x;
    const float* xi = in + (size_t)row * D;
    float vals[3];
    float s0 = 0.f, s1 = 0.f;
    #pragma unroll
    for (int e = 0; e < 3; ++e) {
        float v = xi[tid + e * 256];
        vals[e] = v; s0 += v; s1 += v * v;
    }
    r1[tid] = s0; r2[tid] = s1; __syncthreads();
    for (int st = 128; st > 0; st >>= 1) {
        if (tid < st) { r1[tid] += r1[tid + st]; r2[tid] += r2[tid + st]; }
        __syncthreads();
    }
    float mu  = r1[0] * (1.0f / D);
    float var = r2[0] * (1.0f / D) - mu * mu;
    float rs  = rsqrtf(var + EPS);
    float* xo = out + (size_t)row * D;
    #pragma unroll
    for (int e = 0; e < 3; ++e) {
        int i = tid + e * 256;
        xo[i] = (vals[e] - mu) * rs * g[i] + bb[i];
    }
}

// ---------------------------------------------------------------- fp32 GEMM
// C[M,N] = A[M,K] @ B + bias (+gelu) (+res). BT=0: B is [K,N]; BT=1: B is [N,K].
// 64x64 C-tile, BK=16, 256 threads, 4x4 per thread.
template<int BT, int DO_GELU, int DO_RES>
__global__ __launch_bounds__(256) void gemm_k(const float* __restrict__ A, const float* __restrict__ Bm,
                                              const float* __restrict__ bias, const float* __restrict__ res,
                                              float* __restrict__ C, int Nn, int Kn) {
    __shared__ float As[16][64];
    __shared__ float Bs[16][64];
    int tid = threadIdx.x;
    int tx = tid & 15, ty = tid >> 4;
    int n0 = blockIdx.x * 64, m0 = blockIdx.y * 64;
    float acc[4][4] = {};
    for (int k0 = 0; k0 < Kn; k0 += 16) {
        { // A tile: [64 rows][16 k], row-major fp32, float4 per thread
            int m = tid >> 2, k4 = (tid & 3) * 4;
            float4 a = *(const float4*)(A + (size_t)(m0 + m) * Kn + (k0 + k4));
            As[k4 + 0][m] = a.x; As[k4 + 1][m] = a.y; As[k4 + 2][m] = a.z; As[k4 + 3][m] = a.w;
        }
        if (BT == 0) { // B [K,N]
            int k = tid >> 4, n4 = (tid & 15) * 4;
            float4 b = *(const float4*)(Bm + (size_t)(k0 + k) * Nn + (n0 + n4));
            *(float4*)&Bs[k][n4] = b;
        } else {       // B [N,K] (wte)
            int n = tid >> 2, k4 = (tid & 3) * 4;
            float4 b = make_float4(0.f, 0.f, 0.f, 0.f);
            if (n0 + n < Nn) b = *(const float4*)(Bm + (size_t)(n0 + n) * Kn + (k0 + k4));
            Bs[k4 + 0][n] = b.x; Bs[k4 + 1][n] = b.y; Bs[k4 + 2][n] = b.z; Bs[k4 + 3][n] = b.w;
        }
        __syncthreads();
        #pragma unroll
        for (int k = 0; k < 16; ++k) {
            float4 a = *(const float4*)&As[k][ty * 4];
            float4 b = *(const float4*)&Bs[k][tx * 4];
            float av[4] = {a.x, a.y, a.z, a.w};
            float bv[4] = {b.x, b.y, b.z, b.w};
            #pragma unroll
            for (int i = 0; i < 4; ++i)
                #pragma unroll
                for (int j = 0; j < 4; ++j)
                    acc[i][j] += av[i] * bv[j];
        }
        __syncthreads();
    }
    #pragma unroll
    for (int i = 0; i < 4; ++i) {
        int m = m0 + ty * 4 + i;
        #pragma unroll
        for (int j = 0; j < 4; ++j) {
            int n = n0 + tx * 4 + j;
            if (BT && n >= Nn) continue;
            float vv = acc[i][j];
            if (bias) vv += bias[n];
            if (DO_GELU) vv = 0.5f * vv * (1.0f + erff(vv * 0.70710678118654752f));
            if (DO_RES) vv += res[(size_t)m * Nn + n];
            C[(size_t)m * Nn + n] = vv;
        }
    }
}

// ---------------------------------------------------------------- attention
// one block (256 thr) per (b, h, q-row); scores in LDS; causal softmax; PV.
__global__ __launch_bounds__(256) void attn_k(const float* __restrict__ q, const float* __restrict__ k,
                                              const float* __restrict__ v, float* __restrict__ o) {
    __shared__ float qs[DH];
    __shared__ float sc[S];
    __shared__ float red[256];
    __shared__ float part[4][DH];
    int qi = blockIdx.x, h = blockIdx.y, b = blockIdx.z;
    int tid = threadIdx.x;
    size_t base = (size_t)(b * S) * D + (size_t)h * DH;
    if (tid < DH) qs[tid] = q[base + (size_t)qi * D + tid];
    __syncthreads();
    int nk = qi + 1;
    float lmax = -1e30f;
    for (int j = tid; j < nk; j += 256) {
        const float* krow = k + base + (size_t)j * D;
        float s = 0.f;
        #pragma unroll 16
        for (int d = 0; d < DH; ++d) s += qs[d] * krow[d];
        s *= 0.125f;
        sc[j] = s;
        lmax = fmaxf(lmax, s);
    }
    red[tid] = lmax; __syncthreads();
    for (int st = 128; st > 0; st >>= 1) { if (tid < st) red[tid] = fmaxf(red[tid], red[tid + st]); __syncthreads(); }
    float mx = red[0]; __syncthreads();
    float lsum = 0.f;
    for (int j = tid; j < nk; j += 256) {
        float p = __expf(sc[j] - mx);
        sc[j] = p; lsum += p;
    }
    red[tid] = lsum; __syncthreads();
    for (int st = 128; st > 0; st >>= 1) { if (tid < st) red[tid] += red[tid + st]; __syncthreads(); }
    float inv = 1.0f / red[0];
    int lane = tid & 63, w = tid >> 6;
    float acc = 0.f;
    for (int j = w; j < nk; j += 4) acc += sc[j] * v[base + (size_t)j * D + lane];
    part[w][lane] = acc; __syncthreads();
    if (w == 0)
        o[base + (size_t)qi * D + lane] = (part[0][lane] + part[1][lane] + part[2][lane] + part[3][lane]) * inv;
}

// ---------------------------------------------------------------- launch
extern "C" void kernel_launch(void* const* d_in, const int* in_sizes, int n_in,
                              void* d_out, int out_size, void* d_ws, size_t ws_size,
                              hipStream_t stream) {
    const int*   ids   = (const int*)  d_in[0];
    const float* wte   = (const float*)d_in[1];
    const float* wpe   = (const float*)d_in[2];
    const float* Wq    = (const float*)d_in[3];
    const float* bq    = (const float*)d_in[4];
    const float* Wk    = (const float*)d_in[5];
    const float* bk    = (const float*)d_in[6];
    const float* Wv    = (const float*)d_in[7];
    const float* bv    = (const float*)d_in[8];
    const float* Wo    = (const float*)d_in[9];
    const float* bo    = (const float*)d_in[10];
    const float* Wfc   = (const float*)d_in[11];
    const float* bfc   = (const float*)d_in[12];
    const float* Wproj = (const float*)d_in[13];
    const float* bproj = (const float*)d_in[14];
    const float* ln1g  = (const float*)d_in[15];
    const float* ln1b  = (const float*)d_in[16];
    const float* lnfg  = (const float*)d_in[17];
    const float* lnfb  = (const float*)d_in[18];
    float* out = (float*)d_out;

    float* ws  = (float*)d_ws;
    float* x   = ws;                 // [M, D]
    float* hb  = x  + (size_t)M * D; // [M, D]
    float* qb  = hb + (size_t)M * D; // [M, D]
    float* kb  = qb + (size_t)M * D; // [M, D]
    float* vb  = kb + (size_t)M * D; // [M, D]
    float* ob  = vb + (size_t)M * D; // [M, D]
    float* ff  = qb;                 // [M, F] aliases q/k/v/o (dead by then)

    embed_k<<<M, 256, 0, stream>>>(ids, wte, wpe, x);

    dim3 g768(D / 64, M / 64);
    dim3 gfc(F / 64, M / 64);
    dim3 gattn(S, H, B);

    for (int l = 0; l < L; ++l) {
        ln_k<<<M, 256, 0, stream>>>(x, hb, ln1g + l * D, ln1b + l * D);
        gemm_k<0,0,0><<<g768, 256, 0, stream>>>(hb, Wq + (size_t)l * D * D, bq + l * D, nullptr, qb, D, D);
        gemm_k<0,0,0><<<g768, 256, 0, stream>>>(hb, Wk + (size_t)l * D * D, bk + l * D, nullptr, kb, D, D);
        gemm_k<0,0,0><<<g768, 256, 0, stream>>>(hb, Wv + (size_t)l * D * D, bv + l * D, nullptr, vb, D, D);
        attn_k<<<gattn, 256, 0, stream>>>(qb, kb, vb, ob);
        gemm_k<0,0,1><<<g768, 256, 0, stream>>>(ob, Wo + (size_t)l * D * D, bo + l * D, x, x, D, D);
        gemm_k<0,1,0><<<gfc, 256, 0, stream>>>(x, Wfc + (size_t)l * D * F, bfc + l * F, nullptr, ff, F, D);
        gemm_k<0,0,1><<<g768, 256, 0, stream>>>(ff, Wproj + (size_t)l * F * D, bproj + l * D, x, x, D, F);
    }

    ln_k<<<M, 256, 0, stream>>>(x, hb, lnfg, lnfb);
    dim3 glg((V + 63) / 64, M / 64);
    gemm_k<1,0,0><<<glg, 256, 0, stream>>>(hb, wte, nullptr, nullptr, out, V, D);
}